// Round 7
// baseline (1809.683 us; speedup 1.0000x reference)
//
#include <hip/hip_runtime.h>

#define NAGENTS 32768
#define SLAB    65536            // NAGENTS*2
#define SPLIT   1310720          // 20*SLAB : flat idx below -> traj_abs, above -> out
#define PRED    30
#define IN_F    40
#define LN_EPS  1e-5f
#define APB     64               // agents per block
#define NBLK    (NAGENTS/APB)    // 512 = 2 blocks/CU -> co-resident by construction
#define XSTRIDE 104              // shorts per agent row: 96 used (16 x + 64 h + 16 zero) + 8 pad

typedef short bf16x8 __attribute__((ext_vector_type(8)));
typedef short bf16x4 __attribute__((ext_vector_type(4)));
typedef float f32x4  __attribute__((ext_vector_type(4)));

// cst float offsets
#define C_EMBW 0      // 640
#define C_EMBB 640    // 16
#define C_LN1G 656    // 40
#define C_LN1B 696    // 40
#define C_LN2G 736    // 64
#define C_LN2B 800    // 64
#define C_H2PW 864    // 128
#define C_H2PB 992    // 2
#define C_BIAS 994    // 256 (b_ih + b_hh)
#define C_TOT  1250

__device__ __forceinline__ float fsigmoid(float x){ return 1.f/(1.f+__expf(-x)); }
__device__ __forceinline__ float ftanh(float x){
    float t = __expf(-2.f*fabsf(x));
    float r = (1.f-t)/(1.f+t);
    return copysignf(r, x);
}
__device__ __forceinline__ float lrelu(float x){ return x > 0.f ? x : 0.01f*x; }
__device__ __forceinline__ short f2bf(float x){
    unsigned u = __float_as_uint(x);
    return (short)((u + 0x7FFFu + ((u>>16)&1u)) >> 16);   // RNE
}
__device__ __forceinline__ float bf2f(short s){
    return __uint_as_float(((unsigned)(unsigned short)s) << 16);
}

__global__ __launch_bounds__(256, 2)
void persist_kernel(const float* __restrict__ traj,
                    float* __restrict__ out,
                    const float* __restrict__ dec_h,
                    const float* __restrict__ W_ih, const float* __restrict__ W_hh,
                    const float* __restrict__ b_ih, const float* __restrict__ b_hh,
                    const float* __restrict__ emb_W, const float* __restrict__ emb_b,
                    const float* __restrict__ h2p_W, const float* __restrict__ h2p_b,
                    const float* __restrict__ ln1_g, const float* __restrict__ ln1_b,
                    const float* __restrict__ ln2_g, const float* __restrict__ ln2_b,
                    int* __restrict__ flags)   // ws: [0..NBLK) per-block arrive flags
{
    __shared__ float row[APB*41];       // LN1 input rows, padded
    __shared__ short Xs[APB*XSTRIDE];   // bf16 A-operand [agent][k]: 0..16 x, 16..80 h, 80..96 zero
    __shared__ float cst[C_TOT];

    const int tid = threadIdx.x;
    const int bid = blockIdx.x;
    const int a0  = bid * APB;
    const int l   = tid & 63;
    const int w   = __builtin_amdgcn_readfirstlane(tid >> 6);
    const int cl  = l & 15;
    const int kb  = l >> 4;
    const int nh  = w*16 + cl;          // gate-elem column this lane owns

    // ---- stage constants (once) ----
    for (int i = tid; i < 640; i += 256) cst[C_EMBW+i] = emb_W[i];
    if (tid < 16)  cst[C_EMBB+tid] = emb_b[tid];
    if (tid < 40)  { cst[C_LN1G+tid] = ln1_g[tid]; cst[C_LN1B+tid] = ln1_b[tid]; }
    if (tid < 64)  { cst[C_LN2G+tid] = ln2_g[tid]; cst[C_LN2B+tid] = ln2_b[tid]; }
    if (tid < 128) cst[C_H2PW+tid] = h2p_W[tid];
    if (tid < 2)   cst[C_H2PB+tid] = h2p_b[tid];
    cst[C_BIAS+tid] = b_ih[tid] + b_hh[tid];

    // ---- B fragments (weights) in registers, once for all 30 steps ----
    // Wfull[k][n]: k<16 -> W_ih[n][k]; 16<=k<80 -> W_hh[n][k-16]; else 0
    // (mapping validated by the passing round-4/5/6 runs)
    bf16x8 bw[4][3];
#pragma unroll
    for (int g = 0; g < 4; ++g)
#pragma unroll
        for (int ks = 0; ks < 3; ++ks) {
            int n = g*64 + nh;
            bf16x8 v;
#pragma unroll
            for (int j = 0; j < 8; ++j) {
                int k = ks*32 + kb*8 + j;
                float f = 0.f;
                if (k < 16)      f = W_ih[n*16 + k];
                else if (k < 80) f = W_hh[n*64 + (k-16)];
                v[j] = f2bf(f);
            }
            bw[g][ks] = v;
        }

    // ---- init h region of Xs from dec_h; zero k-pad [80,96) (written once) ----
    for (int i = tid; i < APB*64; i += 256) {
        int a = i >> 6, j = i & 63;
        Xs[a*XSTRIDE + 16 + j] = f2bf(dec_h[(a0 + a)*64 + j]);
    }
    for (int i = tid; i < APB*16; i += 256) {
        int a = i >> 4, k = 80 + (i & 15);
        Xs[a*XSTRIDE + k] = 0;
    }

    // ---- c state fp32 in registers for all 30 steps ----
    float cs[4][4];
#pragma unroll
    for (int mt = 0; mt < 4; ++mt)
#pragma unroll
        for (int r = 0; r < 4; ++r) cs[mt][r] = 0.f;

    __syncthreads();

    for (int s = 0; s < PRED; ++s) {
        // ---- 1. stage LN1 rows: flat sliding window over [traj_abs ++ out] ----
        {
            const int Gb = s*SLAB + a0*IN_F;
            for (int g = tid; g < APB*IN_F; g += 256) {
                int G = Gb + g;
                float v = (G < SPLIT) ? traj[G] : out[G - SPLIT];
                int a = g / IN_F;
                row[a*41 + (g - a*IN_F)] = v;
            }
        }
        __syncthreads();

        // ---- 2. LN1 + embedding + leaky_relu -> Xs[:,0:16) bf16 (4 thr/agent) ----
        {
            int a  = tid & 63;
            int e0 = (tid >> 6) * 4;
            const float* r = row + a*41;
            float sum = 0.f, sq = 0.f;
            for (int f = 0; f < IN_F; ++f) { float v = r[f]; sum += v; sq += v*v; }
            float m   = sum * (1.f/IN_F);
            float var = sq * (1.f/IN_F) - m*m;
            float inv = rsqrtf(var + LN_EPS);
            float x0=0.f, x1=0.f, x2=0.f, x3=0.f;
            for (int f = 0; f < IN_F; ++f) {
                float v = (r[f]-m)*inv*cst[C_LN1G+f] + cst[C_LN1B+f];
                x0 += v * cst[C_EMBW + (e0+0)*IN_F + f];
                x1 += v * cst[C_EMBW + (e0+1)*IN_F + f];
                x2 += v * cst[C_EMBW + (e0+2)*IN_F + f];
                x3 += v * cst[C_EMBW + (e0+3)*IN_F + f];
            }
            bf16x4 xa;
            xa[0] = f2bf(lrelu(x0 + cst[C_EMBB+e0+0]));
            xa[1] = f2bf(lrelu(x1 + cst[C_EMBB+e0+1]));
            xa[2] = f2bf(lrelu(x2 + cst[C_EMBB+e0+2]));
            xa[3] = f2bf(lrelu(x3 + cst[C_EMBB+e0+3]));
            *(bf16x4*)&Xs[a*XSTRIDE + e0] = xa;   // 8B aligned
        }
        __syncthreads();

        // ---- 3. gates GEMM via MFMA: D[agent][g*64+nh], 4 M-tiles ----
        f32x4 acc[4][4];
#pragma unroll
        for (int g = 0; g < 4; ++g) {
            float bb = cst[C_BIAS + g*64 + nh];
#pragma unroll
            for (int mt = 0; mt < 4; ++mt) acc[mt][g] = f32x4{bb, bb, bb, bb};
        }
#pragma unroll
        for (int mt = 0; mt < 4; ++mt) {
            const short* base = &Xs[(mt*16 + cl)*XSTRIDE + kb*8];
            bf16x8 af0 = *(const bf16x8*)(base);        // k 0..31
            bf16x8 af1 = *(const bf16x8*)(base + 32);   // k 32..63
            bf16x8 af2 = *(const bf16x8*)(base + 64);   // k 64..95 (pad zero)
#pragma unroll
            for (int g = 0; g < 4; ++g) {
                acc[mt][g] = __builtin_amdgcn_mfma_f32_16x16x32_bf16(af0, bw[g][0], acc[mt][g], 0, 0, 0);
                acc[mt][g] = __builtin_amdgcn_mfma_f32_16x16x32_bf16(af1, bw[g][1], acc[mt][g], 0, 0, 0);
                acc[mt][g] = __builtin_amdgcn_mfma_f32_16x16x32_bf16(af2, bw[g][2], acc[mt][g], 0, 0, 0);
            }
        }
        __syncthreads();   // all Xs reads done before h overwrite

        // ---- 4. LSTM elementwise (lane-local); h -> Xs bf16, c in regs ----
#pragma unroll
        for (int mt = 0; mt < 4; ++mt) {
            int abase = mt*16 + kb*4;
#pragma unroll
            for (int r = 0; r < 4; ++r) {
                float cn = fsigmoid(acc[mt][1][r]) * cs[mt][r]
                         + fsigmoid(acc[mt][0][r]) * ftanh(acc[mt][2][r]);
                float hn = fsigmoid(acc[mt][3][r]) * ftanh(cn);
                cs[mt][r] = cn;
                Xs[(abase + r)*XSTRIDE + 16 + nh] = f2bf(hn);
            }
        }
        __syncthreads();

        // ---- 5. LN2 + hidden2pos -> out slab s ----
        if (tid < APB*2) {
            int a = tid >> 1, d = tid & 1;
            const bf16x8* hp = (const bf16x8*)&Xs[a*XSTRIDE + 16];
            float sum = 0.f, sq = 0.f;
#pragma unroll
            for (int ch = 0; ch < 8; ++ch) {
                bf16x8 v = hp[ch];
#pragma unroll
                for (int j = 0; j < 8; ++j) { float f = bf2f(v[j]); sum += f; sq += f*f; }
            }
            float m   = sum * (1.f/64);
            float var = sq * (1.f/64) - m*m;
            float inv = rsqrtf(var + LN_EPS);
            float p = cst[C_H2PB + d];
#pragma unroll
            for (int ch = 0; ch < 8; ++ch) {
                bf16x8 v = hp[ch];
#pragma unroll
                for (int j = 0; j < 8; ++j) {
                    int k = ch*8 + j;
                    float f = bf2f(v[j]);
                    p += ((f-m)*inv*cst[C_LN2G+k] + cst[C_LN2B+k]) * cst[C_H2PW + d*64 + k];
                }
            }
            out[s*SLAB + a0*2 + tid] = p;
        }

        // ---- 6. grid barrier: symmetric all-poll-all (skip after last step) ----
        // Poison-safe: flags start 0xAAAAAAAA (negative as signed) < s+1.
        // Release publishes this block's out stores; acquire polls invalidate
        // stale cache before next step's window reads. (Scheme validated r5.)
        if (s != PRED-1) {
            __syncthreads();   // all out stores of this block issued (vmcnt drain)
            if (tid == 0)
                __hip_atomic_store(&flags[bid], s+1, __ATOMIC_RELEASE, __HIP_MEMORY_SCOPE_AGENT);
            for (int j = tid; j < NBLK; j += 256) {
                while (__hip_atomic_load(&flags[j], __ATOMIC_ACQUIRE, __HIP_MEMORY_SCOPE_AGENT) < s+1)
                    __builtin_amdgcn_s_sleep(1);
            }
            __syncthreads();
        }
    }
}

extern "C" void kernel_launch(void* const* d_in, const int* in_sizes, int n_in,
                              void* d_out, int out_size, void* d_ws, size_t ws_size,
                              hipStream_t stream) {
    const float* traj  = (const float*)d_in[0];
    // d_in[1] = traj_rel (unused)
    const float* dec_h = (const float*)d_in[2];
    const float* W_ih  = (const float*)d_in[3];
    const float* W_hh  = (const float*)d_in[4];
    const float* b_ih  = (const float*)d_in[5];
    const float* b_hh  = (const float*)d_in[6];
    const float* emb_W = (const float*)d_in[7];
    const float* emb_b = (const float*)d_in[8];
    const float* h2p_W = (const float*)d_in[9];
    const float* h2p_b = (const float*)d_in[10];
    const float* ln1_g = (const float*)d_in[11];
    const float* ln1_b = (const float*)d_in[12];
    const float* ln2_g = (const float*)d_in[13];
    const float* ln2_b = (const float*)d_in[14];
    float* out = (float*)d_out;
    int*   flg = (int*)d_ws;

    persist_kernel<<<NBLK, 256, 0, stream>>>(
        traj, out, dec_h, W_ih, W_hh, b_ih, b_hh, emb_W, emb_b,
        h2p_W, h2p_b, ln1_g, ln1_b, ln2_g, ln2_b, flg);
}

// Round 8
// 1034.251 us; speedup vs baseline: 1.7498x; 1.7498x over previous
//
#include <hip/hip_runtime.h>

#define NAGENTS 32768
#define SLAB    65536            // NAGENTS*2
#define SPLIT   1310720          // 20*SLAB : flat idx below -> traj_abs, above -> out
#define PRED    30
#define IN_F    40
#define LN_EPS  1e-5f
#define APB     64               // agents per block
#define NBLK    (NAGENTS/APB)    // 512 = 2 blocks/CU -> all co-resident by construction
#define XSTRIDE 104              // shorts per agent row: 96 used (16 x + 64 h + 16 zero) + 8 pad

typedef short bf16x8 __attribute__((ext_vector_type(8)));
typedef short bf16x4 __attribute__((ext_vector_type(4)));
typedef float f32x4  __attribute__((ext_vector_type(4)));

// cst float offsets
#define C_EMBW 0      // 640
#define C_EMBB 640    // 16
#define C_LN1G 656    // 40
#define C_LN1B 696    // 40
#define C_LN2G 736    // 64
#define C_LN2B 800    // 64
#define C_H2PW 864    // 128
#define C_H2PB 992    // 2
#define C_BIAS 994    // 256 (b_ih + b_hh)
#define C_TOT  1250

__device__ __forceinline__ float fsigmoid(float x){ return 1.f/(1.f+__expf(-x)); }
__device__ __forceinline__ float ftanh(float x){
    float t = __expf(-2.f*fabsf(x));
    float r = (1.f-t)/(1.f+t);
    return copysignf(r, x);
}
__device__ __forceinline__ float lrelu(float x){ return x > 0.f ? x : 0.01f*x; }
__device__ __forceinline__ short f2bf(float x){
    unsigned u = __float_as_uint(x);
    return (short)((u + 0x7FFFu + ((u>>16)&1u)) >> 16);   // RNE
}
__device__ __forceinline__ float bf2f(short s){
    return __uint_as_float(((unsigned)(unsigned short)s) << 16);
}

__global__ __launch_bounds__(256, 2)
void persist_kernel(const float* __restrict__ traj,
                    float* __restrict__ out,
                    const float* __restrict__ dec_h,
                    const float* __restrict__ W_ih, const float* __restrict__ W_hh,
                    const float* __restrict__ b_ih, const float* __restrict__ b_hh,
                    const float* __restrict__ emb_W, const float* __restrict__ emb_b,
                    const float* __restrict__ h2p_W, const float* __restrict__ h2p_b,
                    const float* __restrict__ ln1_g, const float* __restrict__ ln1_b,
                    const float* __restrict__ ln2_g, const float* __restrict__ ln2_b,
                    int* __restrict__ flags)   // ws: flags[b] = # steps block b completed
{
    __shared__ float row[APB*41];       // LN1 input rows, padded
    __shared__ short Xs[APB*XSTRIDE];   // bf16 A-operand [agent][k]: 0..16 x, 16..80 h, 80..96 zero
    __shared__ float cst[C_TOT];

    const int tid = threadIdx.x;
    const int bid = blockIdx.x;
    const int a0  = bid * APB;
    const int l   = tid & 63;
    const int w   = __builtin_amdgcn_readfirstlane(tid >> 6);
    const int cl  = l & 15;
    const int kb  = l >> 4;
    const int nh  = w*16 + cl;          // gate-elem column this lane owns

    // ---- stage constants (once) ----
    for (int i = tid; i < 640; i += 256) cst[C_EMBW+i] = emb_W[i];
    if (tid < 16)  cst[C_EMBB+tid] = emb_b[tid];
    if (tid < 40)  { cst[C_LN1G+tid] = ln1_g[tid]; cst[C_LN1B+tid] = ln1_b[tid]; }
    if (tid < 64)  { cst[C_LN2G+tid] = ln2_g[tid]; cst[C_LN2B+tid] = ln2_b[tid]; }
    if (tid < 128) cst[C_H2PW+tid] = h2p_W[tid];
    if (tid < 2)   cst[C_H2PB+tid] = h2p_b[tid];
    cst[C_BIAS+tid] = b_ih[tid] + b_hh[tid];

    // ---- B fragments (weights) in registers, once for all 30 steps ----
    // Wfull[k][n]: k<16 -> W_ih[n][k]; 16<=k<80 -> W_hh[n][k-16]; else 0
    bf16x8 bw[4][3];
#pragma unroll
    for (int g = 0; g < 4; ++g)
#pragma unroll
        for (int ks = 0; ks < 3; ++ks) {
            int n = g*64 + nh;
            bf16x8 v;
#pragma unroll
            for (int j = 0; j < 8; ++j) {
                int k = ks*32 + kb*8 + j;
                float f = 0.f;
                if (k < 16)      f = W_ih[n*16 + k];
                else if (k < 80) f = W_hh[n*64 + (k-16)];
                v[j] = f2bf(f);
            }
            bw[g][ks] = v;
        }

    // ---- init h region of Xs from dec_h; zero k-pad [80,96) (written once) ----
    for (int i = tid; i < APB*64; i += 256) {
        int a = i >> 6, j = i & 63;
        Xs[a*XSTRIDE + 16 + j] = f2bf(dec_h[(a0 + a)*64 + j]);
    }
    for (int i = tid; i < APB*16; i += 256) {
        int a = i >> 4, k = 80 + (i & 15);
        Xs[a*XSTRIDE + k] = 0;
    }

    // ---- c state fp32 in registers for all 30 steps ----
    float cs[4][4];
#pragma unroll
    for (int mt = 0; mt < 4; ++mt)
#pragma unroll
        for (int r = 0; r < 4; ++r) cs[mt][r] = 0.f;

    __syncthreads();

    for (int s = 0; s < PRED; ++s) {
        // ---- 0. wait for exactly the producer chunks this block's window needs ----
        // Window reads out-flat O in [Gb-SPLIT, Gb-SPLIT+2560). Chunk = 128 floats
        // (one producer block's slab piece). Chunk i: t = i>>9, p = i&511.
        // Need flags[p] >= t+1. <=21 chunks, spanning <=2 slabs; most are >=2
        // steps stale -> no spin. Poison 0xAAAAAAAA is negative -> waits work.
        {
            const long Gb   = (long)s*SLAB + (long)a0*IN_F;
            const long Oend = Gb + APB*IN_F - SPLIT;   // exclusive
            if (Oend > 0) {
                long O0 = Gb - SPLIT; if (O0 < 0) O0 = 0;
                int i0 = (int)(O0 >> 7);
                int i1 = (int)((Oend - 1) >> 7);
                for (int i = i0 + tid; i <= i1; i += 256) {
                    int t = i >> 9, p = i & 511;
                    while (__hip_atomic_load(&flags[p], __ATOMIC_RELAXED,
                                             __HIP_MEMORY_SCOPE_AGENT) < t + 1)
                        __builtin_amdgcn_s_sleep(1);
                }
                __threadfence();   // acquire: invalidate stale cache before window reads
            }
        }
        __syncthreads();

        // ---- 1. stage LN1 rows: flat sliding window over [traj_abs ++ out] ----
        {
            const int Gb = s*SLAB + a0*IN_F;
            for (int g = tid; g < APB*IN_F; g += 256) {
                int G = Gb + g;
                float v = (G < SPLIT) ? traj[G] : out[G - SPLIT];
                int a = g / IN_F;
                row[a*41 + (g - a*IN_F)] = v;
            }
        }
        __syncthreads();

        // ---- 2. LN1 + embedding + leaky_relu -> Xs[:,0:16) bf16 (4 thr/agent) ----
        {
            int a  = tid & 63;
            int e0 = (tid >> 6) * 4;
            const float* r = row + a*41;
            float sum = 0.f, sq = 0.f;
            for (int f = 0; f < IN_F; ++f) { float v = r[f]; sum += v; sq += v*v; }
            float m   = sum * (1.f/IN_F);
            float var = sq * (1.f/IN_F) - m*m;
            float inv = rsqrtf(var + LN_EPS);
            float x0=0.f, x1=0.f, x2=0.f, x3=0.f;
            for (int f = 0; f < IN_F; ++f) {
                float v = (r[f]-m)*inv*cst[C_LN1G+f] + cst[C_LN1B+f];
                x0 += v * cst[C_EMBW + (e0+0)*IN_F + f];
                x1 += v * cst[C_EMBW + (e0+1)*IN_F + f];
                x2 += v * cst[C_EMBW + (e0+2)*IN_F + f];
                x3 += v * cst[C_EMBW + (e0+3)*IN_F + f];
            }
            bf16x4 xa;
            xa[0] = f2bf(lrelu(x0 + cst[C_EMBB+e0+0]));
            xa[1] = f2bf(lrelu(x1 + cst[C_EMBB+e0+1]));
            xa[2] = f2bf(lrelu(x2 + cst[C_EMBB+e0+2]));
            xa[3] = f2bf(lrelu(x3 + cst[C_EMBB+e0+3]));
            *(bf16x4*)&Xs[a*XSTRIDE + e0] = xa;   // 8B aligned
        }
        __syncthreads();

        // ---- 3. gates GEMM via MFMA: D[agent][g*64+nh], 4 M-tiles ----
        f32x4 acc[4][4];
#pragma unroll
        for (int g = 0; g < 4; ++g) {
            float bb = cst[C_BIAS + g*64 + nh];
#pragma unroll
            for (int mt = 0; mt < 4; ++mt) acc[mt][g] = f32x4{bb, bb, bb, bb};
        }
#pragma unroll
        for (int mt = 0; mt < 4; ++mt) {
            const short* base = &Xs[(mt*16 + cl)*XSTRIDE + kb*8];
            bf16x8 af0 = *(const bf16x8*)(base);        // k 0..31
            bf16x8 af1 = *(const bf16x8*)(base + 32);   // k 32..63
            bf16x8 af2 = *(const bf16x8*)(base + 64);   // k 64..95 (pad zero)
#pragma unroll
            for (int g = 0; g < 4; ++g) {
                acc[mt][g] = __builtin_amdgcn_mfma_f32_16x16x32_bf16(af0, bw[g][0], acc[mt][g], 0, 0, 0);
                acc[mt][g] = __builtin_amdgcn_mfma_f32_16x16x32_bf16(af1, bw[g][1], acc[mt][g], 0, 0, 0);
                acc[mt][g] = __builtin_amdgcn_mfma_f32_16x16x32_bf16(af2, bw[g][2], acc[mt][g], 0, 0, 0);
            }
        }
        __syncthreads();   // all Xs reads done before h overwrite

        // ---- 4. LSTM elementwise (lane-local); h -> Xs bf16, c in regs ----
#pragma unroll
        for (int mt = 0; mt < 4; ++mt) {
            int abase = mt*16 + kb*4;
#pragma unroll
            for (int r = 0; r < 4; ++r) {
                float cn = fsigmoid(acc[mt][1][r]) * cs[mt][r]
                         + fsigmoid(acc[mt][0][r]) * ftanh(acc[mt][2][r]);
                float hn = fsigmoid(acc[mt][3][r]) * ftanh(cn);
                cs[mt][r] = cn;
                Xs[(abase + r)*XSTRIDE + 16 + nh] = f2bf(hn);
            }
        }
        __syncthreads();

        // ---- 5. LN2 + hidden2pos -> out slab s ----
        if (tid < APB*2) {
            int a = tid >> 1, d = tid & 1;
            const bf16x8* hp = (const bf16x8*)&Xs[a*XSTRIDE + 16];
            float sum = 0.f, sq = 0.f;
#pragma unroll
            for (int ch = 0; ch < 8; ++ch) {
                bf16x8 v = hp[ch];
#pragma unroll
                for (int j = 0; j < 8; ++j) { float f = bf2f(v[j]); sum += f; sq += f*f; }
            }
            float m   = sum * (1.f/64);
            float var = sq * (1.f/64) - m*m;
            float inv = rsqrtf(var + LN_EPS);
            float p = cst[C_H2PB + d];
#pragma unroll
            for (int ch = 0; ch < 8; ++ch) {
                bf16x8 v = hp[ch];
#pragma unroll
                for (int j = 0; j < 8; ++j) {
                    int k = ch*8 + j;
                    float f = bf2f(v[j]);
                    p += ((f-m)*inv*cst[C_LN2G+k] + cst[C_LN2B+k]) * cst[C_H2PW + d*64 + k];
                }
            }
            out[s*SLAB + a0*2 + tid] = p;
        }

        // ---- 6. publish progress (skip after last step) ----
        if (s != PRED-1) {
            __syncthreads();   // all out stores of this block drained (vmcnt 0 at barrier)
            if (tid == 0)
                __hip_atomic_store(&flags[bid], s+1, __ATOMIC_RELEASE,
                                   __HIP_MEMORY_SCOPE_AGENT);
        }
    }
}

extern "C" void kernel_launch(void* const* d_in, const int* in_sizes, int n_in,
                              void* d_out, int out_size, void* d_ws, size_t ws_size,
                              hipStream_t stream) {
    const float* traj  = (const float*)d_in[0];
    // d_in[1] = traj_rel (unused)
    const float* dec_h = (const float*)d_in[2];
    const float* W_ih  = (const float*)d_in[3];
    const float* W_hh  = (const float*)d_in[4];
    const float* b_ih  = (const float*)d_in[5];
    const float* b_hh  = (const float*)d_in[6];
    const float* emb_W = (const float*)d_in[7];
    const float* emb_b = (const float*)d_in[8];
    const float* h2p_W = (const float*)d_in[9];
    const float* h2p_b = (const float*)d_in[10];
    const float* ln1_g = (const float*)d_in[11];
    const float* ln1_b = (const float*)d_in[12];
    const float* ln2_g = (const float*)d_in[13];
    const float* ln2_b = (const float*)d_in[14];
    float* out = (float*)d_out;
    int*   flg = (int*)d_ws;

    persist_kernel<<<NBLK, 256, 0, stream>>>(
        traj, out, dec_h, W_ih, W_hh, b_ih, b_hh, emb_W, emb_b,
        h2p_W, h2p_b, ln1_g, ln1_b, ln2_g, ln2_b, flg);
}

// Round 9
// 486.285 us; speedup vs baseline: 3.7214x; 2.1268x over previous
//
#include <hip/hip_runtime.h>

#define NAGENTS 32768
#define SLAB    65536            // NAGENTS*2
#define SPLIT   1310720          // 20*SLAB : flat idx below -> traj_abs, above -> out
#define PRED    30
#define IN_F    40
#define LN_EPS  1e-5f
#define APB     64               // agents per block
#define NBLK    (NAGENTS/APB)    // 512 = 2 blocks/CU -> all co-resident by construction
#define XSTRIDE 104              // shorts per agent row: 96 used (16 x + 64 h + 16 zero) + 8 pad

typedef short bf16x8 __attribute__((ext_vector_type(8)));
typedef short bf16x4 __attribute__((ext_vector_type(4)));
typedef float f32x4  __attribute__((ext_vector_type(4)));

// cst float offsets
#define C_EMBW 0      // 640
#define C_EMBB 640    // 16
#define C_LN1G 656    // 40
#define C_LN1B 696    // 40
#define C_LN2G 736    // 64
#define C_LN2B 800    // 64
#define C_H2PW 864    // 128
#define C_H2PB 992    // 2
#define C_BIAS 994    // 256 (b_ih + b_hh)
#define C_TOT  1250

__device__ __forceinline__ float fsigmoid(float x){ return 1.f/(1.f+__expf(-x)); }
__device__ __forceinline__ float ftanh(float x){
    float t = __expf(-2.f*fabsf(x));
    float r = (1.f-t)/(1.f+t);
    return copysignf(r, x);
}
__device__ __forceinline__ float lrelu(float x){ return x > 0.f ? x : 0.01f*x; }
__device__ __forceinline__ short f2bf(float x){
    unsigned u = __float_as_uint(x);
    return (short)((u + 0x7FFFu + ((u>>16)&1u)) >> 16);   // RNE
}
__device__ __forceinline__ float bf2f(short s){
    return __uint_as_float(((unsigned)(unsigned short)s) << 16);
}

__global__ __launch_bounds__(256, 2)
void persist_kernel(const float* __restrict__ traj,
                    float* __restrict__ out,
                    const float* __restrict__ dec_h,
                    const float* __restrict__ W_ih, const float* __restrict__ W_hh,
                    const float* __restrict__ b_ih, const float* __restrict__ b_hh,
                    const float* __restrict__ emb_W, const float* __restrict__ emb_b,
                    const float* __restrict__ h2p_W, const float* __restrict__ h2p_b,
                    const float* __restrict__ ln1_g, const float* __restrict__ ln1_b,
                    const float* __restrict__ ln2_g, const float* __restrict__ ln2_b,
                    int* __restrict__ flags)   // ws: flags[b] = # steps block b completed
{
    __shared__ float row[APB*41];       // LN1 input rows, padded
    __shared__ short Xs[APB*XSTRIDE];   // bf16 A-operand [agent][k]: 0..16 x, 16..80 h, 80..96 zero
    __shared__ float cst[C_TOT];

    const int tid = threadIdx.x;
    const int bid = blockIdx.x;
    const int a0  = bid * APB;
    const int l   = tid & 63;
    const int w   = __builtin_amdgcn_readfirstlane(tid >> 6);
    const int cl  = l & 15;
    const int kb  = l >> 4;
    const int nh  = w*16 + cl;          // gate-elem column this lane owns

    // ---- stage constants (once) ----
    for (int i = tid; i < 640; i += 256) cst[C_EMBW+i] = emb_W[i];
    if (tid < 16)  cst[C_EMBB+tid] = emb_b[tid];
    if (tid < 40)  { cst[C_LN1G+tid] = ln1_g[tid]; cst[C_LN1B+tid] = ln1_b[tid]; }
    if (tid < 64)  { cst[C_LN2G+tid] = ln2_g[tid]; cst[C_LN2B+tid] = ln2_b[tid]; }
    if (tid < 128) cst[C_H2PW+tid] = h2p_W[tid];
    if (tid < 2)   cst[C_H2PB+tid] = h2p_b[tid];
    cst[C_BIAS+tid] = b_ih[tid] + b_hh[tid];

    // ---- B fragments (weights) in registers, once for all 30 steps ----
    // Wfull[k][n]: k<16 -> W_ih[n][k]; 16<=k<80 -> W_hh[n][k-16]; else 0
    bf16x8 bw[4][3];
#pragma unroll
    for (int g = 0; g < 4; ++g)
#pragma unroll
        for (int ks = 0; ks < 3; ++ks) {
            int n = g*64 + nh;
            bf16x8 v;
#pragma unroll
            for (int j = 0; j < 8; ++j) {
                int k = ks*32 + kb*8 + j;
                float f = 0.f;
                if (k < 16)      f = W_ih[n*16 + k];
                else if (k < 80) f = W_hh[n*64 + (k-16)];
                v[j] = f2bf(f);
            }
            bw[g][ks] = v;
        }

    // ---- init h region of Xs from dec_h; zero k-pad [80,96) (written once) ----
    for (int i = tid; i < APB*64; i += 256) {
        int a = i >> 6, j = i & 63;
        Xs[a*XSTRIDE + 16 + j] = f2bf(dec_h[(a0 + a)*64 + j]);
    }
    for (int i = tid; i < APB*16; i += 256) {
        int a = i >> 4, k = 80 + (i & 15);
        Xs[a*XSTRIDE + k] = 0;
    }

    // ---- c state fp32 in registers for all 30 steps ----
    float cs[4][4];
#pragma unroll
    for (int mt = 0; mt < 4; ++mt)
#pragma unroll
        for (int r = 0; r < 4; ++r) cs[mt][r] = 0.f;

    __syncthreads();

    for (int s = 0; s < PRED; ++s) {
        // ---- 0. wait for exactly the producer chunks this block's window needs ----
        // Chunk = 128 floats (one producer block's slab piece); chunk i:
        // slab t = i>>9, producer p = i&511; need flags[p] >= t+1.
        // ACQUIRE poll: load sc1 + buffer_inv per iteration (usually 1) is the
        // only cache-maintenance op in the hot loop. Out data itself was
        // written via agent-relaxed atomic stores (write-through to MALL), so
        // no wbl2 is needed anywhere. Poison 0xAAAAAAAA is negative -> waits ok.
        {
            const long Gb   = (long)s*SLAB + (long)a0*IN_F;
            const long Oend = Gb + APB*IN_F - SPLIT;   // exclusive
            if (Oend > 0) {
                long O0 = Gb - SPLIT; if (O0 < 0) O0 = 0;
                int i0 = (int)(O0 >> 7);
                int i1 = (int)((Oend - 1) >> 7);
                for (int i = i0 + tid; i <= i1; i += 256) {
                    int t = i >> 9, p = i & 511;
                    while (__hip_atomic_load(&flags[p], __ATOMIC_ACQUIRE,
                                             __HIP_MEMORY_SCOPE_AGENT) < t + 1)
                        __builtin_amdgcn_s_sleep(1);
                }
            }
        }
        __syncthreads();

        // ---- 1. stage LN1 rows: flat sliding window over [traj_abs ++ out] ----
        {
            const int Gb = s*SLAB + a0*IN_F;
            for (int g = tid; g < APB*IN_F; g += 256) {
                int G = Gb + g;
                float v = (G < SPLIT) ? traj[G] : out[G - SPLIT];
                int a = g / IN_F;
                row[a*41 + (g - a*IN_F)] = v;
            }
        }
        __syncthreads();

        // ---- 2. LN1 + embedding + leaky_relu -> Xs[:,0:16) bf16 (4 thr/agent) ----
        {
            int a  = tid & 63;
            int e0 = (tid >> 6) * 4;
            const float* r = row + a*41;
            float sum = 0.f, sq = 0.f;
            for (int f = 0; f < IN_F; ++f) { float v = r[f]; sum += v; sq += v*v; }
            float m   = sum * (1.f/IN_F);
            float var = sq * (1.f/IN_F) - m*m;
            float inv = rsqrtf(var + LN_EPS);
            float x0=0.f, x1=0.f, x2=0.f, x3=0.f;
            for (int f = 0; f < IN_F; ++f) {
                float v = (r[f]-m)*inv*cst[C_LN1G+f] + cst[C_LN1B+f];
                x0 += v * cst[C_EMBW + (e0+0)*IN_F + f];
                x1 += v * cst[C_EMBW + (e0+1)*IN_F + f];
                x2 += v * cst[C_EMBW + (e0+2)*IN_F + f];
                x3 += v * cst[C_EMBW + (e0+3)*IN_F + f];
            }
            bf16x4 xa;
            xa[0] = f2bf(lrelu(x0 + cst[C_EMBB+e0+0]));
            xa[1] = f2bf(lrelu(x1 + cst[C_EMBB+e0+1]));
            xa[2] = f2bf(lrelu(x2 + cst[C_EMBB+e0+2]));
            xa[3] = f2bf(lrelu(x3 + cst[C_EMBB+e0+3]));
            *(bf16x4*)&Xs[a*XSTRIDE + e0] = xa;   // 8B aligned
        }
        __syncthreads();

        // ---- 3. gates GEMM via MFMA: D[agent][g*64+nh], 4 M-tiles ----
        f32x4 acc[4][4];
#pragma unroll
        for (int g = 0; g < 4; ++g) {
            float bb = cst[C_BIAS + g*64 + nh];
#pragma unroll
            for (int mt = 0; mt < 4; ++mt) acc[mt][g] = f32x4{bb, bb, bb, bb};
        }
#pragma unroll
        for (int mt = 0; mt < 4; ++mt) {
            const short* base = &Xs[(mt*16 + cl)*XSTRIDE + kb*8];
            bf16x8 af0 = *(const bf16x8*)(base);        // k 0..31
            bf16x8 af1 = *(const bf16x8*)(base + 32);   // k 32..63
            bf16x8 af2 = *(const bf16x8*)(base + 64);   // k 64..95 (pad zero)
#pragma unroll
            for (int g = 0; g < 4; ++g) {
                acc[mt][g] = __builtin_amdgcn_mfma_f32_16x16x32_bf16(af0, bw[g][0], acc[mt][g], 0, 0, 0);
                acc[mt][g] = __builtin_amdgcn_mfma_f32_16x16x32_bf16(af1, bw[g][1], acc[mt][g], 0, 0, 0);
                acc[mt][g] = __builtin_amdgcn_mfma_f32_16x16x32_bf16(af2, bw[g][2], acc[mt][g], 0, 0, 0);
            }
        }
        __syncthreads();   // all Xs reads done before h overwrite

        // ---- 4. LSTM elementwise (lane-local); h -> Xs bf16, c in regs ----
#pragma unroll
        for (int mt = 0; mt < 4; ++mt) {
            int abase = mt*16 + kb*4;
#pragma unroll
            for (int r = 0; r < 4; ++r) {
                float cn = fsigmoid(acc[mt][1][r]) * cs[mt][r]
                         + fsigmoid(acc[mt][0][r]) * ftanh(acc[mt][2][r]);
                float hn = fsigmoid(acc[mt][3][r]) * ftanh(cn);
                cs[mt][r] = cn;
                Xs[(abase + r)*XSTRIDE + 16 + nh] = f2bf(hn);
            }
        }
        __syncthreads();

        // ---- 5. LN2 + hidden2pos -> out slab s (write-through atomic stores) ----
        if (tid < APB*2) {
            int a = tid >> 1, d = tid & 1;
            const bf16x8* hp = (const bf16x8*)&Xs[a*XSTRIDE + 16];
            float sum = 0.f, sq = 0.f;
#pragma unroll
            for (int ch = 0; ch < 8; ++ch) {
                bf16x8 v = hp[ch];
#pragma unroll
                for (int j = 0; j < 8; ++j) { float f = bf2f(v[j]); sum += f; sq += f*f; }
            }
            float m   = sum * (1.f/64);
            float var = sq * (1.f/64) - m*m;
            float inv = rsqrtf(var + LN_EPS);
            float p = cst[C_H2PB + d];
#pragma unroll
            for (int ch = 0; ch < 8; ++ch) {
                bf16x8 v = hp[ch];
#pragma unroll
                for (int j = 0; j < 8; ++j) {
                    int k = ch*8 + j;
                    float f = bf2f(v[j]);
                    p += ((f-m)*inv*cst[C_LN2G+k] + cst[C_LN2B+k]) * cst[C_H2PW + d*64 + k];
                }
            }
            // agent-scope relaxed atomic store: bypasses/write-through L2 so the
            // value is at the device coherence point without any wbl2 fence.
            __hip_atomic_store(&out[s*SLAB + a0*2 + tid], p,
                               __ATOMIC_RELAXED, __HIP_MEMORY_SCOPE_AGENT);
        }

        // ---- 6. publish progress: RELAXED flag store (skip after last step) ----
        // __syncthreads() drains vmcnt(0) block-wide, so all out stores have
        // reached MALL before the flag store is issued. No release fence needed.
        if (s != PRED-1) {
            __syncthreads();
            if (tid == 0)
                __hip_atomic_store(&flags[bid], s+1, __ATOMIC_RELAXED,
                                   __HIP_MEMORY_SCOPE_AGENT);
        }
    }
}

extern "C" void kernel_launch(void* const* d_in, const int* in_sizes, int n_in,
                              void* d_out, int out_size, void* d_ws, size_t ws_size,
                              hipStream_t stream) {
    const float* traj  = (const float*)d_in[0];
    // d_in[1] = traj_rel (unused)
    const float* dec_h = (const float*)d_in[2];
    const float* W_ih  = (const float*)d_in[3];
    const float* W_hh  = (const float*)d_in[4];
    const float* b_ih  = (const float*)d_in[5];
    const float* b_hh  = (const float*)d_in[6];
    const float* emb_W = (const float*)d_in[7];
    const float* emb_b = (const float*)d_in[8];
    const float* h2p_W = (const float*)d_in[9];
    const float* h2p_b = (const float*)d_in[10];
    const float* ln1_g = (const float*)d_in[11];
    const float* ln1_b = (const float*)d_in[12];
    const float* ln2_g = (const float*)d_in[13];
    const float* ln2_b = (const float*)d_in[14];
    float* out = (float*)d_out;
    int*   flg = (int*)d_ws;

    persist_kernel<<<NBLK, 256, 0, stream>>>(
        traj, out, dec_h, W_ih, W_hh, b_ih, b_hh, emb_W, emb_b,
        h2p_W, h2p_b, ln1_g, ln1_b, ln2_g, ln2_b, flg);
}

// Round 10
// 400.757 us; speedup vs baseline: 4.5157x; 1.2134x over previous
//
#include <hip/hip_runtime.h>

#define NAGENTS 32768
#define SLAB    65536            // NAGENTS*2
#define SPLIT   1310720          // 20*SLAB : flat idx below -> traj_abs, above -> out
#define SPLIT4  327680           // SPLIT/4
#define PRED    30
#define IN_F    40
#define LN_EPS  1e-5f
#define APB     128              // agents per block
#define NBLK    (NAGENTS/APB)    // 256 = 1 block/CU -> co-resident by construction
#define BTH     1024
#define XSTRIDE 104              // shorts per agent row: 96 used (16 x + 64 h + 16 zero) + 8 pad
#define RPITCH  44               // floats per staged row (40 used, /4 aligned)

typedef short bf16x8 __attribute__((ext_vector_type(8)));
typedef short bf16x4 __attribute__((ext_vector_type(4)));
typedef short bf16x2 __attribute__((ext_vector_type(2)));
typedef float f32x4  __attribute__((ext_vector_type(4)));

// cst float offsets (LN weights folded into following linears)
#define C_GWT  0      // 640 : gWT[f*16+e] = ln1g[f]*embW[e,f]
#define C_SGW  640    // 16  : sum_f gWT
#define C_BW   656    // 16  : sum_f ln1b[f]*embW[e,f] + emb_b[e]
#define C_G2   672    // 128 : g2WT[k*2+d] = ln2g[k]*h2pW[d,k]
#define C_SG2  800    // 2
#define C_B2   802    // 2   : sum_k ln2b[k]*h2pW[d,k] + h2p_b[d]
#define C_BIAS 804    // 256 : b_ih + b_hh
#define C_TOT  1060

__device__ __forceinline__ float fsigmoid(float x){ return 1.f/(1.f+__expf(-x)); }
__device__ __forceinline__ float ftanh(float x){
    float t = __expf(-2.f*fabsf(x));
    float r = (1.f-t)/(1.f+t);
    return copysignf(r, x);
}
__device__ __forceinline__ float lrelu(float x){ return x > 0.f ? x : 0.01f*x; }
__device__ __forceinline__ short f2bf(float x){
    unsigned u = __float_as_uint(x);
    return (short)((u + 0x7FFFu + ((u>>16)&1u)) >> 16);   // RNE
}
__device__ __forceinline__ float bf2f(short s){
    return __uint_as_float(((unsigned)(unsigned short)s) << 16);
}

__global__ __launch_bounds__(BTH, 4)
void persist_kernel(const float* __restrict__ traj,
                    float* __restrict__ out,
                    const float* __restrict__ dec_h,
                    const float* __restrict__ W_ih, const float* __restrict__ W_hh,
                    const float* __restrict__ b_ih, const float* __restrict__ b_hh,
                    const float* __restrict__ emb_W, const float* __restrict__ emb_b,
                    const float* __restrict__ h2p_W, const float* __restrict__ h2p_b,
                    const float* __restrict__ ln1_g, const float* __restrict__ ln1_b,
                    const float* __restrict__ ln2_g, const float* __restrict__ ln2_b,
                    int* __restrict__ flags)   // ws: flags[b] = # steps block b completed
{
    __shared__ float row[APB*RPITCH];   // staged LN1 input rows
    __shared__ short Xs[APB*XSTRIDE];   // bf16 A-operand [agent][k]: 0..16 x, 16..80 h, 80..96 zero
    __shared__ float cst[C_TOT];

    const int tid  = threadIdx.x;
    const int bid  = blockIdx.x;
    const int a0   = bid * APB;
    const int l    = tid & 63;
    const int wv   = tid >> 6;            // 0..15
    const int gang = wv >> 2;             // 0..3 : 32 agents each
    const int wvin = wv & 3;              // wave-in-gang
    const int cl   = l & 15;
    const int kb   = l >> 4;
    const int nh   = wvin*16 + cl;        // gate-elem column this lane owns

    // ---- one-time folded-constant precompute (per block) ----
    if (tid < 640) {
        int e = tid / 40, f = tid - e*40;
        cst[C_GWT + f*16 + e] = ln1_g[f] * emb_W[e*40 + f];
    }
    if (tid < 16) {
        int e = tid;
        float s = 0.f, b = 0.f;
        for (int f = 0; f < IN_F; ++f) {
            float wf = emb_W[e*40 + f];
            s += ln1_g[f] * wf;
            b += ln1_b[f] * wf;
        }
        cst[C_SGW + e] = s;
        cst[C_BW + e]  = b + emb_b[e];
    }
    if (tid < 128) {
        int k = tid >> 1, d = tid & 1;
        cst[C_G2 + tid] = ln2_g[k] * h2p_W[d*64 + k];
    }
    if (tid < 2) {
        int d = tid;
        float s = 0.f, b = 0.f;
        for (int k = 0; k < 64; ++k) {
            float wf = h2p_W[d*64 + k];
            s += ln2_g[k] * wf;
            b += ln2_b[k] * wf;
        }
        cst[C_SG2 + d] = s;
        cst[C_B2 + d]  = b + h2p_b[d];
    }
    if (tid < 256) cst[C_BIAS + tid] = b_ih[tid] + b_hh[tid];

    // ---- B fragments (weights) in registers, once for all 30 steps ----
    // Wfull[k][n]: k<16 -> W_ih[n][k]; 16<=k<80 -> W_hh[n][k-16]; else 0
    bf16x8 bw[4][3];
#pragma unroll
    for (int g = 0; g < 4; ++g)
#pragma unroll
        for (int ks = 0; ks < 3; ++ks) {
            int n = g*64 + nh;
            bf16x8 v;
#pragma unroll
            for (int j = 0; j < 8; ++j) {
                int k = ks*32 + kb*8 + j;
                float f = 0.f;
                if (k < 16)      f = W_ih[n*16 + k];
                else if (k < 80) f = W_hh[n*64 + (k-16)];
                v[j] = f2bf(f);
            }
            bw[g][ks] = v;
        }

    // ---- init h region of Xs from dec_h (float4 reads); zero k-pad ----
    for (int i = tid; i < APB*16; i += BTH) {       // 16 float4 per agent
        int a = i >> 4, q = i & 15;
        float4 hv = ((const float4*)dec_h)[(a0 + a)*16 + q];
        bf16x4 hb;
        hb[0] = f2bf(hv.x); hb[1] = f2bf(hv.y);
        hb[2] = f2bf(hv.z); hb[3] = f2bf(hv.w);
        *(bf16x4*)&Xs[a*XSTRIDE + 16 + q*4] = hb;
    }
    if (tid < APB*2) {
        int a = tid >> 1, hf = tid & 1;
        *(bf16x8*)&Xs[a*XSTRIDE + 80 + hf*8] = bf16x8{0,0,0,0,0,0,0,0};
    }

    // ---- c state fp32 in registers for all 30 steps ----
    float cs[2][4];
#pragma unroll
    for (int mt = 0; mt < 2; ++mt)
#pragma unroll
        for (int r = 0; r < 4; ++r) cs[mt][r] = 0.f;

    __syncthreads();

    for (int s = 0; s < PRED; ++s) {
        // ---- 0. wait for producer chunks this block's window needs ----
        // Chunk = 256 floats (one producer's slab piece): i>>8 = slab t,
        // i&255 = producer p; need flags[p] >= t+1. <=21 chunks; acquire poll
        // is the only cache-maintenance op in the loop (round-9-validated).
        {
            const long Ob = (long)s*SLAB + (long)a0*IN_F - SPLIT;
            const long Oe = Ob + APB*IN_F;    // exclusive
            if (Oe > 0) {
                long o0 = Ob < 0 ? 0 : Ob;
                int i0 = (int)(o0 >> 8);
                int i1 = (int)((Oe - 1) >> 8);
                for (int i = i0 + tid; i <= i1; i += BTH) {
                    int t = i >> 8, p = i & 255;
                    while (__hip_atomic_load(&flags[p], __ATOMIC_ACQUIRE,
                                             __HIP_MEMORY_SCOPE_AGENT) < t + 1)
                        __builtin_amdgcn_s_sleep(1);
                }
            }
        }
        __syncthreads();

        // ---- 1. stage rows, float4 over the flat window [traj_abs ++ out] ----
        {
            const int Gb4 = s*(SLAB/4) + bid*(APB*IN_F/4);   // 16B-aligned base
            for (int i = tid; i < APB*IN_F/4; i += BTH) {    // 1280 float4
                int a = i / 10, f4 = i - a*10;
                int G4 = Gb4 + i;
                float4 v = (G4 < SPLIT4) ? ((const float4*)traj)[G4]
                                         : ((const float4*)out)[G4 - SPLIT4];
                *(float4*)&row[a*RPITCH + f4*4] = v;
            }
        }
        __syncthreads();

        // ---- 2. LN1 stats (split 8-way) + folded emb -> Xs[:,0:16) ----
        {
            int a = tid >> 3, p = tid & 7;    // 8 threads/agent, wave-local
            const float* r = row + a*RPITCH;
            float s1 = 0.f, s2 = 0.f;
#pragma unroll
            for (int j = 0; j < 5; ++j) { float v = r[p*5 + j]; s1 += v; s2 += v*v; }
#pragma unroll
            for (int mk = 1; mk < 8; mk <<= 1) {
                s1 += __shfl_xor(s1, mk, 64);
                s2 += __shfl_xor(s2, mk, 64);
            }
            float m   = s1 * (1.f/IN_F);
            float inv = rsqrtf(s2*(1.f/IN_F) - m*m + LN_EPS);
            int e0 = p*2;
            float d0 = 0.f, d1 = 0.f;
            for (int f = 0; f < IN_F; ++f) {
                float v = r[f];                                   // LDS broadcast
                float2 gw = *(const float2*)&cst[C_GWT + f*16 + e0];
                d0 += v*gw.x; d1 += v*gw.y;
            }
            float x0 = inv*(d0 - m*cst[C_SGW+e0  ]) + cst[C_BW+e0  ];
            float x1 = inv*(d1 - m*cst[C_SGW+e0+1]) + cst[C_BW+e0+1];
            bf16x2 xa;
            xa[0] = f2bf(lrelu(x0));
            xa[1] = f2bf(lrelu(x1));
            *(bf16x2*)&Xs[a*XSTRIDE + e0] = xa;
        }
        __syncthreads();

        // ---- 3. gates GEMM via MFMA: gang handles 32 agents, 2 M-tiles ----
        f32x4 acc[2][4];
#pragma unroll
        for (int g = 0; g < 4; ++g) {
            float bb = cst[C_BIAS + g*64 + nh];
            acc[0][g] = f32x4{bb, bb, bb, bb};
            acc[1][g] = f32x4{bb, bb, bb, bb};
        }
#pragma unroll
        for (int mt = 0; mt < 2; ++mt) {
            const short* base = &Xs[(gang*32 + mt*16 + cl)*XSTRIDE + kb*8];
            bf16x8 af0 = *(const bf16x8*)(base);        // k 0..31
            bf16x8 af1 = *(const bf16x8*)(base + 32);   // k 32..63
            bf16x8 af2 = *(const bf16x8*)(base + 64);   // k 64..95 (pad zero)
#pragma unroll
            for (int g = 0; g < 4; ++g) {
                acc[mt][g] = __builtin_amdgcn_mfma_f32_16x16x32_bf16(af0, bw[g][0], acc[mt][g], 0, 0, 0);
                acc[mt][g] = __builtin_amdgcn_mfma_f32_16x16x32_bf16(af1, bw[g][1], acc[mt][g], 0, 0, 0);
                acc[mt][g] = __builtin_amdgcn_mfma_f32_16x16x32_bf16(af2, bw[g][2], acc[mt][g], 0, 0, 0);
            }
        }
        __syncthreads();   // all Xs reads done before h overwrite

        // ---- 4. LSTM elementwise (lane-local); h -> Xs bf16, c in regs ----
#pragma unroll
        for (int mt = 0; mt < 2; ++mt) {
            int abase = gang*32 + mt*16 + kb*4;
#pragma unroll
            for (int r = 0; r < 4; ++r) {
                float cn = fsigmoid(acc[mt][1][r]) * cs[mt][r]
                         + fsigmoid(acc[mt][0][r]) * ftanh(acc[mt][2][r]);
                float hn = fsigmoid(acc[mt][3][r]) * ftanh(cn);
                cs[mt][r] = cn;
                Xs[(abase + r)*XSTRIDE + 16 + nh] = f2bf(hn);
            }
        }
        __syncthreads();

        // ---- 5. LN2 (split 8-way) + folded h2p -> out (write-through) ----
        {
            int a = tid >> 3, p = tid & 7;
            bf16x8 hv = *(const bf16x8*)&Xs[a*XSTRIDE + 16 + p*8];
            float s1 = 0.f, s2 = 0.f, d0 = 0.f, d1 = 0.f;
#pragma unroll
            for (int j = 0; j < 8; ++j) {
                float f = bf2f(hv[j]);
                float2 gw = *(const float2*)&cst[C_G2 + (p*8 + j)*2];
                s1 += f; s2 += f*f;
                d0 += f*gw.x; d1 += f*gw.y;
            }
#pragma unroll
            for (int mk = 1; mk < 8; mk <<= 1) {
                s1 += __shfl_xor(s1, mk, 64);
                s2 += __shfl_xor(s2, mk, 64);
                d0 += __shfl_xor(d0, mk, 64);
                d1 += __shfl_xor(d1, mk, 64);
            }
            if (p < 2) {
                float m   = s1 * (1.f/64);
                float inv = rsqrtf(s2*(1.f/64) - m*m + LN_EPS);
                float dd  = (p == 0) ? d0 : d1;
                float val = inv*(dd - m*cst[C_SG2+p]) + cst[C_B2+p];
                // agent-scope relaxed atomic store: write-through to the
                // coherence point, no wbl2 fence anywhere (round-9-validated).
                __hip_atomic_store(&out[s*SLAB + (a0 + a)*2 + p], val,
                                   __ATOMIC_RELAXED, __HIP_MEMORY_SCOPE_AGENT);
            }
        }

        // ---- 6. publish progress: relaxed flag store after vmcnt drain ----
        if (s != PRED-1) {
            __syncthreads();
            if (tid == 0)
                __hip_atomic_store(&flags[bid], s+1, __ATOMIC_RELAXED,
                                   __HIP_MEMORY_SCOPE_AGENT);
        }
    }
}

extern "C" void kernel_launch(void* const* d_in, const int* in_sizes, int n_in,
                              void* d_out, int out_size, void* d_ws, size_t ws_size,
                              hipStream_t stream) {
    const float* traj  = (const float*)d_in[0];
    // d_in[1] = traj_rel (unused)
    const float* dec_h = (const float*)d_in[2];
    const float* W_ih  = (const float*)d_in[3];
    const float* W_hh  = (const float*)d_in[4];
    const float* b_ih  = (const float*)d_in[5];
    const float* b_hh  = (const float*)d_in[6];
    const float* emb_W = (const float*)d_in[7];
    const float* emb_b = (const float*)d_in[8];
    const float* h2p_W = (const float*)d_in[9];
    const float* h2p_b = (const float*)d_in[10];
    const float* ln1_g = (const float*)d_in[11];
    const float* ln1_b = (const float*)d_in[12];
    const float* ln2_g = (const float*)d_in[13];
    const float* ln2_b = (const float*)d_in[14];
    float* out = (float*)d_out;
    int*   flg = (int*)d_ws;

    persist_kernel<<<NBLK, BTH, 0, stream>>>(
        traj, out, dec_h, W_ih, W_hh, b_ih, b_hh, emb_W, emb_b,
        h2p_W, h2p_b, ln1_g, ln1_b, ln2_g, ln2_b, flg);
}

// Round 11
// 370.802 us; speedup vs baseline: 4.8805x; 1.0808x over previous
//
#include <hip/hip_runtime.h>

#define NAGENTS 32768
#define SLAB    65536            // NAGENTS*2
#define SPLIT   1310720          // 20*SLAB : flat idx below -> traj_abs, above -> out
#define SPLIT4  327680           // SPLIT/4
#define PRED    30
#define IN_F    40
#define LN_EPS  1e-5f
#define APB     128              // agents per block
#define NBLK    (NAGENTS/APB)    // 256 = 1 block/CU -> co-resident by construction
#define BTH     1024
#define XSTRIDE 104              // shorts per agent row in Xs (96 used + 8 pad)
#define RSTR    72               // shorts per agent row in Rs (64 used: 40 data + 24 zero, + 8 pad)

typedef short bf16x8 __attribute__((ext_vector_type(8)));
typedef short bf16x4 __attribute__((ext_vector_type(4)));
typedef short bf16x2 __attribute__((ext_vector_type(2)));
typedef float f32x4  __attribute__((ext_vector_type(4)));

// cst float offsets (LN weights folded into following linears)
#define C_SGW  0      // 16  : sum_f ln1g[f]*embW[e,f]
#define C_BW   16     // 16  : sum_f ln1b[f]*embW[e,f] + emb_b[e]
#define C_G2   32     // 128 : g2WT[k*2+d] = ln2g[k]*h2pW[d,k]
#define C_SG2  160    // 2
#define C_B2   162    // 2
#define C_BIAS 164    // 256 : b_ih + b_hh
#define C_TOT  420

__device__ __forceinline__ float fsigmoid(float x){ return 1.f/(1.f+__expf(-x)); }
__device__ __forceinline__ float ftanh(float x){
    float t = __expf(-2.f*fabsf(x));
    float r = (1.f-t)/(1.f+t);
    return copysignf(r, x);
}
__device__ __forceinline__ float lrelu(float x){ return x > 0.f ? x : 0.01f*x; }
__device__ __forceinline__ short f2bf(float x){
    unsigned u = __float_as_uint(x);
    return (short)((u + 0x7FFFu + ((u>>16)&1u)) >> 16);   // RNE
}
__device__ __forceinline__ float bf2f(short s){
    return __uint_as_float(((unsigned)(unsigned short)s) << 16);
}

__global__ __launch_bounds__(BTH, 4)
void persist_kernel(const float* __restrict__ traj,
                    float* __restrict__ out,
                    const float* __restrict__ dec_h,
                    const float* __restrict__ W_ih, const float* __restrict__ W_hh,
                    const float* __restrict__ b_ih, const float* __restrict__ b_hh,
                    const float* __restrict__ emb_W, const float* __restrict__ emb_b,
                    const float* __restrict__ h2p_W, const float* __restrict__ h2p_b,
                    const float* __restrict__ ln1_g, const float* __restrict__ ln1_b,
                    const float* __restrict__ ln2_g, const float* __restrict__ ln2_b,
                    int* __restrict__ flags)   // ws: flags[b] = # steps block b completed
{
    __shared__ short Rs[APB*RSTR];      // bf16 window rows, A-layout, k-pad zeroed
    __shared__ short Xs[APB*XSTRIDE];   // bf16 A-operand [agent][k]: 0..16 x, 16..80 h, 80..96 zero
    __shared__ float Ds[APB*16];        // embedding dot outputs
    __shared__ float St[APB*2];         // LN1 stats: m, inv per agent
    __shared__ float cst[C_TOT];

    const int tid  = threadIdx.x;
    const int bid  = blockIdx.x;
    const int a0   = bid * APB;
    const int l    = tid & 63;
    const int wv   = tid >> 6;            // 0..15
    const int gang = wv >> 2;             // 0..3 : 32 agents each (gates GEMM)
    const int wvin = wv & 3;              // wave-in-gang
    const int cl   = l & 15;
    const int kb   = l >> 4;
    const int nh   = wvin*16 + cl;        // gate-elem column this lane owns

    // ---- one-time folded-constant precompute (per block) ----
    if (tid < 16) {
        int e = tid;
        float s = 0.f, b = 0.f;
        for (int f = 0; f < IN_F; ++f) {
            float wf = emb_W[e*40 + f];
            s += ln1_g[f] * wf;
            b += ln1_b[f] * wf;
        }
        cst[C_SGW + e] = s;
        cst[C_BW + e]  = b + emb_b[e];
    }
    if (tid < 128) {
        int k = tid >> 1, d = tid & 1;
        cst[C_G2 + tid] = ln2_g[k] * h2p_W[d*64 + k];
    }
    if (tid < 2) {
        int d = tid;
        float s = 0.f, b = 0.f;
        for (int k = 0; k < 64; ++k) {
            float wf = h2p_W[d*64 + k];
            s += ln2_g[k] * wf;
            b += ln2_b[k] * wf;
        }
        cst[C_SG2 + d] = s;
        cst[C_B2 + d]  = b + h2p_b[d];
    }
    if (tid >= 256 && tid < 512) cst[C_BIAS + tid - 256] = b_ih[tid-256] + b_hh[tid-256];

    // ---- gates-B fragments (weights), once for all 30 steps ----
    // Wfull[k][n]: k<16 -> W_ih[n][k]; 16<=k<80 -> W_hh[n][k-16]; else 0
    bf16x8 bw[4][3];
#pragma unroll
    for (int g = 0; g < 4; ++g)
#pragma unroll
        for (int ks = 0; ks < 3; ++ks) {
            int n = g*64 + nh;
            bf16x8 v;
#pragma unroll
            for (int j = 0; j < 8; ++j) {
                int k = ks*32 + kb*8 + j;
                float f = 0.f;
                if (k < 16)      f = W_ih[n*16 + k];
                else if (k < 80) f = W_hh[n*64 + (k-16)];
                v[j] = f2bf(f);
            }
            bw[g][ks] = v;
        }

    // ---- embedding-B fragments: B[k=f][n=e] = ln1g[f]*embW[e,f], K-pad 0 ----
    bf16x8 ew[2];
#pragma unroll
    for (int ks = 0; ks < 2; ++ks) {
        bf16x8 v;
#pragma unroll
        for (int j = 0; j < 8; ++j) {
            int k = ks*32 + kb*8 + j;
            float f = (k < IN_F) ? ln1_g[k] * emb_W[cl*40 + k] : 0.f;
            v[j] = f2bf(f);
        }
        ew[ks] = v;
    }

    // ---- init h region of Xs from dec_h; zero pads (written once) ----
    for (int i = tid; i < APB*16; i += BTH) {       // 16 float4 per agent
        int a = i >> 4, q = i & 15;
        float4 hv = ((const float4*)dec_h)[(a0 + a)*16 + q];
        bf16x4 hb;
        hb[0] = f2bf(hv.x); hb[1] = f2bf(hv.y);
        hb[2] = f2bf(hv.z); hb[3] = f2bf(hv.w);
        *(bf16x4*)&Xs[a*XSTRIDE + 16 + q*4] = hb;
    }
    if (tid < APB*2) {      // Xs k-pad [80,96)
        int a = tid >> 1, hf = tid & 1;
        *(bf16x8*)&Xs[a*XSTRIDE + 80 + hf*8] = bf16x8{0,0,0,0,0,0,0,0};
    }
    for (int i = tid; i < APB*3; i += BTH) {   // Rs k-pad [40,64): 3 bf16x8 per agent
        int a = i / 3, seg = i - a*3;
        *(bf16x8*)&Rs[a*RSTR + 40 + seg*8] = bf16x8{0,0,0,0,0,0,0,0};
    }

    // ---- c state fp32 in registers for all 30 steps ----
    float cs[2][4];
#pragma unroll
    for (int mt = 0; mt < 2; ++mt)
#pragma unroll
        for (int r = 0; r < 4; ++r) cs[mt][r] = 0.f;

    __syncthreads();

    for (int s = 0; s < PRED; ++s) {
        // ---- 0. wait for producer chunks this block's window needs ----
        // Chunk = 256 floats (one producer's slab piece): t = i>>8, p = i&255.
        // Acquire poll is the only cache-maintenance op (round-9-validated).
        {
            const long Ob = (long)s*SLAB + (long)a0*IN_F - SPLIT;
            const long Oe = Ob + APB*IN_F;    // exclusive
            if (Oe > 0) {
                long o0 = Ob < 0 ? 0 : Ob;
                int i0 = (int)(o0 >> 8);
                int i1 = (int)((Oe - 1) >> 8);
                for (int i = i0 + tid; i <= i1; i += BTH) {
                    int t = i >> 8, p = i & 255;
                    while (__hip_atomic_load(&flags[p], __ATOMIC_ACQUIRE,
                                             __HIP_MEMORY_SCOPE_AGENT) < t + 1)
                        __builtin_amdgcn_s_sleep(1);
                }
            }
        }
        __syncthreads();

        // ---- 1. stage rows: float4 global -> bf16x4 Rs (A-layout) ----
        {
            const int Gb4 = s*(SLAB/4) + bid*(APB*IN_F/4);   // 16B-aligned base
            for (int i = tid; i < APB*IN_F/4; i += BTH) {    // 1280 float4
                int a = i / 10, f4 = i - a*10;
                int G4 = Gb4 + i;
                float4 v = (G4 < SPLIT4) ? ((const float4*)traj)[G4]
                                         : ((const float4*)out)[G4 - SPLIT4];
                bf16x4 b;
                b[0] = f2bf(v.x); b[1] = f2bf(v.y);
                b[2] = f2bf(v.z); b[3] = f2bf(v.w);
                *(bf16x4*)&Rs[a*RSTR + f4*4] = b;
            }
        }
        __syncthreads();

        // ---- 2a. embedding GEMM (waves 0-7): D[a][e], K=64 (pad zero) ----
        if (wv < 8) {
            f32x4 dacc = f32x4{0.f, 0.f, 0.f, 0.f};
            const short* base = &Rs[(wv*16 + cl)*RSTR + kb*8];
            bf16x8 a0f = *(const bf16x8*)(base);        // k 0..31
            bf16x8 a1f = *(const bf16x8*)(base + 32);   // k 32..63
            dacc = __builtin_amdgcn_mfma_f32_16x16x32_bf16(a0f, ew[0], dacc, 0, 0, 0);
            dacc = __builtin_amdgcn_mfma_f32_16x16x32_bf16(a1f, ew[1], dacc, 0, 0, 0);
#pragma unroll
            for (int r = 0; r < 4; ++r)
                Ds[(wv*16 + kb*4 + r)*16 + cl] = dacc[r];
        } else {
        // ---- 2b. LN1 stats (waves 8-15): 4 thr/agent, fp-exact over bf16 ----
            int t2 = tid - 512;               // 0..511
            int a = t2 >> 2, p = t2 & 3;
            const bf16x8* rp = (const bf16x8*)&Rs[a*RSTR + p*16];
            bf16x8 v0 = rp[0], v1 = rp[1];    // k-pad zeros don't affect sums
            float s1 = 0.f, s2 = 0.f;
#pragma unroll
            for (int j = 0; j < 8; ++j) {
                float f0 = bf2f(v0[j]), f1 = bf2f(v1[j]);
                s1 += f0 + f1; s2 += f0*f0 + f1*f1;
            }
            s1 += __shfl_xor(s1, 1, 64); s2 += __shfl_xor(s2, 1, 64);
            s1 += __shfl_xor(s1, 2, 64); s2 += __shfl_xor(s2, 2, 64);
            if (p == 0) {
                float m = s1 * (1.f/IN_F);
                St[a*2]   = m;
                St[a*2+1] = rsqrtf(s2*(1.f/IN_F) - m*m + LN_EPS);
            }
        }
        __syncthreads();

        // ---- 3. embedding epilogue: x = inv*(D - m*sgW) + bW, lrelu -> Xs ----
        {
            int a = tid >> 3, p = tid & 7, e0 = p*2;
            float m = St[a*2], inv = St[a*2+1];
            float D0 = Ds[a*16 + e0], D1 = Ds[a*16 + e0 + 1];
            float x0 = inv*(D0 - m*cst[C_SGW+e0  ]) + cst[C_BW+e0  ];
            float x1 = inv*(D1 - m*cst[C_SGW+e0+1]) + cst[C_BW+e0+1];
            bf16x2 xa;
            xa[0] = f2bf(lrelu(x0));
            xa[1] = f2bf(lrelu(x1));
            *(bf16x2*)&Xs[a*XSTRIDE + e0] = xa;
        }
        __syncthreads();

        // ---- 4. gates GEMM via MFMA: gang handles 32 agents, 2 M-tiles ----
        f32x4 acc[2][4];
#pragma unroll
        for (int g = 0; g < 4; ++g) {
            float bb = cst[C_BIAS + g*64 + nh];
            acc[0][g] = f32x4{bb, bb, bb, bb};
            acc[1][g] = f32x4{bb, bb, bb, bb};
        }
#pragma unroll
        for (int mt = 0; mt < 2; ++mt) {
            const short* base = &Xs[(gang*32 + mt*16 + cl)*XSTRIDE + kb*8];
            bf16x8 af0 = *(const bf16x8*)(base);        // k 0..31
            bf16x8 af1 = *(const bf16x8*)(base + 32);   // k 32..63
            bf16x8 af2 = *(const bf16x8*)(base + 64);   // k 64..95 (pad zero)
#pragma unroll
            for (int g = 0; g < 4; ++g) {
                acc[mt][g] = __builtin_amdgcn_mfma_f32_16x16x32_bf16(af0, bw[g][0], acc[mt][g], 0, 0, 0);
                acc[mt][g] = __builtin_amdgcn_mfma_f32_16x16x32_bf16(af1, bw[g][1], acc[mt][g], 0, 0, 0);
                acc[mt][g] = __builtin_amdgcn_mfma_f32_16x16x32_bf16(af2, bw[g][2], acc[mt][g], 0, 0, 0);
            }
        }
        __syncthreads();   // all Xs reads done before h overwrite

        // ---- 5. LSTM elementwise (lane-local); h -> Xs bf16, c in regs ----
#pragma unroll
        for (int mt = 0; mt < 2; ++mt) {
            int abase = gang*32 + mt*16 + kb*4;
#pragma unroll
            for (int r = 0; r < 4; ++r) {
                float cn = fsigmoid(acc[mt][1][r]) * cs[mt][r]
                         + fsigmoid(acc[mt][0][r]) * ftanh(acc[mt][2][r]);
                float hn = fsigmoid(acc[mt][3][r]) * ftanh(cn);
                cs[mt][r] = cn;
                Xs[(abase + r)*XSTRIDE + 16 + nh] = f2bf(hn);
            }
        }
        __syncthreads();

        // ---- 6. LN2 (split 8-way) + folded h2p -> out (write-through) ----
        {
            int a = tid >> 3, p = tid & 7;
            bf16x8 hv = *(const bf16x8*)&Xs[a*XSTRIDE + 16 + p*8];
            float s1 = 0.f, s2 = 0.f, d0 = 0.f, d1 = 0.f;
#pragma unroll
            for (int j = 0; j < 8; ++j) {
                float f = bf2f(hv[j]);
                float2 gw = *(const float2*)&cst[C_G2 + (p*8 + j)*2];
                s1 += f; s2 += f*f;
                d0 += f*gw.x; d1 += f*gw.y;
            }
#pragma unroll
            for (int mk = 1; mk < 8; mk <<= 1) {
                s1 += __shfl_xor(s1, mk, 64);
                s2 += __shfl_xor(s2, mk, 64);
                d0 += __shfl_xor(d0, mk, 64);
                d1 += __shfl_xor(d1, mk, 64);
            }
            if (p < 2) {
                float m   = s1 * (1.f/64);
                float inv = rsqrtf(s2*(1.f/64) - m*m + LN_EPS);
                float dd  = (p == 0) ? d0 : d1;
                float val = inv*(dd - m*cst[C_SG2+p]) + cst[C_B2+p];
                __hip_atomic_store(&out[s*SLAB + (a0 + a)*2 + p], val,
                                   __ATOMIC_RELAXED, __HIP_MEMORY_SCOPE_AGENT);
            }
        }

        // ---- 7. publish progress: relaxed flag store after vmcnt drain ----
        if (s != PRED-1) {
            __syncthreads();
            if (tid == 0)
                __hip_atomic_store(&flags[bid], s+1, __ATOMIC_RELAXED,
                                   __HIP_MEMORY_SCOPE_AGENT);
        }
    }
}

extern "C" void kernel_launch(void* const* d_in, const int* in_sizes, int n_in,
                              void* d_out, int out_size, void* d_ws, size_t ws_size,
                              hipStream_t stream) {
    const float* traj  = (const float*)d_in[0];
    // d_in[1] = traj_rel (unused)
    const float* dec_h = (const float*)d_in[2];
    const float* W_ih  = (const float*)d_in[3];
    const float* W_hh  = (const float*)d_in[4];
    const float* b_ih  = (const float*)d_in[5];
    const float* b_hh  = (const float*)d_in[6];
    const float* emb_W = (const float*)d_in[7];
    const float* emb_b = (const float*)d_in[8];
    const float* h2p_W = (const float*)d_in[9];
    const float* h2p_b = (const float*)d_in[10];
    const float* ln1_g = (const float*)d_in[11];
    const float* ln1_b = (const float*)d_in[12];
    const float* ln2_g = (const float*)d_in[13];
    const float* ln2_b = (const float*)d_in[14];
    float* out = (float*)d_out;
    int*   flg = (int*)d_ws;

    persist_kernel<<<NBLK, BTH, 0, stream>>>(
        traj, out, dec_h, W_ih, W_hh, b_ih, b_hh, emb_W, emb_b,
        h2p_W, h2p_b, ln1_g, ln1_b, ln2_g, ln2_b, flg);
}